// Round 12
// baseline (136.591 us; speedup 1.0000x reference)
//
#include <hip/hip_runtime.h>
#include <math.h>

#define NPTS 4096
#define KNN  20
#define NOUT 64
#define WPB  8               // waves per block
#define QPW  4               // queries per wave
#define QBLK (WPB * QPW)     // 32 queries per block
#define BLKT (WPB * 64)      // 512 threads
#define PCAP 96              // per-query survivor pool capacity
#define HALF 1536            // candidates staged in LDS

// monotone float->uint map (total order preserved)
__device__ __forceinline__ unsigned ord32(float f) {
    unsigned u = __float_as_uint(f);
    int m = ((int)u) >> 31;
    return u ^ ((unsigned)m | 0x80000000u);
}
// inverse of ord32
__device__ __forceinline__ float iord32(unsigned r) {
    unsigned u = (r & 0x80000000u) ? (r ^ 0x80000000u) : ~r;
    return __uint_as_float(u);
}
__device__ __forceinline__ int mbcnt64(unsigned long long m) {
    return __builtin_amdgcn_mbcnt_hi((unsigned)(m >> 32),
           __builtin_amdgcn_mbcnt_lo((unsigned)m, 0));
}

// prologue: xq[b][j] = (x0, x1, x2, -(x0^2+x1^2+x2^2))
__global__ __launch_bounds__(256) void pack_kernel(const float* __restrict__ x,
                                                   float4* __restrict__ xq) {
    const int i = blockIdx.x * 256 + threadIdx.x;   // over B*NPTS
    const int b = i >> 12, j = i & (NPTS - 1);
    const float* xb = x + (size_t)b * 3 * NPTS;
    const float a0 = xb[j], a1 = xb[NPTS + j], a2 = xb[2 * NPTS + j];
    xq[i] = make_float4(a0, a1, a2, -fmaf(a0, a0, fmaf(a1, a1, a2 * a2)));
}

__global__ __launch_bounds__(BLKT, 6) void edgeconv_kernel(
    const float4* __restrict__ xq,    // (B, N) packed points
    const float* __restrict__ Wm,     // (64, 6)
    const float* __restrict__ gamma,
    const float* __restrict__ beta,
    const float* __restrict__ mean,
    const float* __restrict__ var,
    float* __restrict__ out)          // (B, 64, N)
{
    const int bid = blockIdx.x;
    const int b   = bid >> 7;                    // 128 blocks per batch
    const int n0  = (bid & 127) * QBLK;
    const int t    = threadIdx.x;
    const int lane = t & 63;
    const int w    = t >> 6;

    __shared__ float4 tile[HALF];                       // 24 KB
    __shared__ unsigned long long pool[QBLK * PCAP];    // 24 KB; outT aliases it
    __shared__ int cnt[QBLK];

    const float4* xqb = xq + (size_t)b * NPTS;

    if (lane < QPW) cnt[QPW * w + lane] = 0;

    // ---- query constants (scalar loads; pv reloaded later for epilogue) ----
    const int na = __builtin_amdgcn_readfirstlane(n0 + QPW * w);
    float q0[QPW], q1[QPW], q2[QPW];
    #pragma unroll
    for (int q = 0; q < QPW; ++q) {
        const float4 pv = xqb[na + q];
        q0[q] = 2.f * pv.x; q1[q] = 2.f * pv.y; q2[q] = 2.f * pv.z;
    }

    float vm0[QPW], vm1[QPW];
    #pragma unroll
    for (int q = 0; q < QPW; ++q) { vm0[q] = -INFINITY; vm1[q] = -INFINITY; }

    // ---- stage LDS tile; fold staged candidates into group-1 maxima ----
    #pragma unroll
    for (int k2 = 0; k2 < HALF / BLKT; ++k2) {          // 3 iters
        const int c = t + k2 * BLKT;
        const float4 cc = xqb[c];
        tile[c] = cc;
        #pragma unroll
        for (int q = 0; q < QPW; ++q) {
            const float e = fmaf(q0[q], cc.x, fmaf(q1[q], cc.y, fmaf(q2[q], cc.z, cc.w)));
            vm1[q] = fmaxf(vm1[q], e);
        }
    }

    // ---- G1: stream global candidates, lane maxima (2 groups/lane) ----
    #pragma unroll
    for (int g = 0; g < 10; ++g) {
        float4 cc[4];
        #pragma unroll
        for (int u = 0; u < 4; ++u) cc[u] = xqb[HALF + (g * 4 + u) * 64 + lane];
        #pragma unroll
        for (int u = 0; u < 4; ++u) {
            #pragma unroll
            for (int q = 0; q < QPW; ++q) {
                const float e = fmaf(q0[q], cc[u].x, fmaf(q1[q], cc[u].y, fmaf(q2[q], cc[u].z, cc[u].w)));
                if (g < 5) vm0[q] = fmaxf(vm0[q], e);
                else       vm1[q] = fmaxf(vm1[q], e);
            }
        }
    }

    // ---- T[q] ~ 20th-largest of 128 group maxima (16-bit ballot bsearch) ----
    // Any T <= exact 20th works (>=20 distinct candidates >= T => superset safe).
    float Tf[QPW];
    #pragma unroll
    for (int q = 0; q < QPW; ++q) {
        const unsigned h0 = ord32(vm0[q]) >> 16;
        const unsigned h1 = ord32(vm1[q]) >> 16;
        unsigned K = 0;
        #pragma unroll
        for (int bit = 15; bit >= 0; --bit) {
            const unsigned p = K | (1u << bit);
            const int c = __popcll(__ballot(h0 >= p)) + __popcll(__ballot(h1 >= p));
            if (c >= KNN) K = p;
        }
        Tf[q] = iord32(K << 16);
    }

    __syncthreads();   // tile staged; cnt[] initialized

    const int invl = (NPTS - 1) - lane;

    // ---- pass L: LDS tile, fused filter+append ----
    #pragma unroll
    for (int g = 0; g < 6; ++g) {
        float4 cc[4];
        #pragma unroll
        for (int u = 0; u < 4; ++u) cc[u] = tile[(g * 4 + u) * 64 + lane];
        #pragma unroll
        for (int u = 0; u < 4; ++u) {
            const unsigned tag = (unsigned)(invl - (g * 4 + u) * 64);
            #pragma unroll
            for (int q = 0; q < QPW; ++q) {
                const float e = fmaf(q0[q], cc[u].x, fmaf(q1[q], cc[u].y, fmaf(q2[q], cc[u].z, cc[u].w)));
                if (e >= Tf[q]) {
                    const int pos = atomicAdd(&cnt[QPW * w + q], 1);
                    if (pos < PCAP)
                        pool[(QPW * w + q) * PCAP + pos] =
                            ((unsigned long long)ord32(e) << 32) | tag;
                }
            }
        }
    }

    // ---- pass G2: global candidates again, fused filter+append ----
    #pragma unroll
    for (int g = 0; g < 10; ++g) {
        float4 cc[4];
        #pragma unroll
        for (int u = 0; u < 4; ++u) cc[u] = xqb[HALF + (g * 4 + u) * 64 + lane];
        #pragma unroll
        for (int u = 0; u < 4; ++u) {
            const unsigned tag = (unsigned)(invl - HALF - (g * 4 + u) * 64);
            #pragma unroll
            for (int q = 0; q < QPW; ++q) {
                const float e = fmaf(q0[q], cc[u].x, fmaf(q1[q], cc[u].y, fmaf(q2[q], cc[u].z, cc[u].w)));
                if (e >= Tf[q]) {
                    const int pos = atomicAdd(&cnt[QPW * w + q], 1);
                    if (pos < PCAP)
                        pool[(QPW * w + q) * PCAP + pos] =
                            ((unsigned long long)ord32(e) << 32) | tag;
                }
            }
        }
    }

    // ---- exact top-20 set per query: 32-bit ballot bsearch, 2 entries/lane ----
    unsigned myidx[QPW];
    #pragma unroll
    for (int q = 0; q < QPW; ++q) {
        const int pr = QPW * w + q;
        unsigned long long* pl = pool + (size_t)pr * PCAP;
        int cw = __builtin_amdgcn_readfirstlane(cnt[pr]);
        if (cw > PCAP) cw = PCAP;                      // >= 20 guaranteed

        // sentinel 0: ord32(finite) >= 1, so invalid entries never counted
        const unsigned long long e0 = (lane < cw) ? pl[lane] : 0ull;
        const unsigned long long e1 = (lane + 64 < cw) ? pl[lane + 64] : 0ull;
        const unsigned k0 = (unsigned)(e0 >> 32), t0 = (unsigned)e0;
        const unsigned k1 = (unsigned)(e1 >> 32), t1 = (unsigned)e1;

        unsigned K = 0;
        #pragma unroll
        for (int bit = 31; bit >= 0; --bit) {
            const unsigned p = K | (1u << bit);
            const int c = __popcll(__ballot(k0 >= p)) + __popcll(__ballot(k1 >= p));
            if (c >= KNN) K = p;
        }

        unsigned long long g0 = __ballot(k0 > K);
        unsigned long long g1 = __ballot(k1 > K);
        const int m = __popcll(g0) + __popcll(g1);     // <= 19
        unsigned long long s0 = __ballot(k0 == K);
        unsigned long long s1 = __ballot(k1 == K);
        const int r = KNN - m;                         // >= 1 ties needed
        if (__popcll(s0) + __popcll(s1) > r) {
            // tie split: choose r ties with largest tag (= lowest index)
            unsigned TT = 0;
            #pragma unroll
            for (int bit = 11; bit >= 0; --bit) {      // tags < 4096
                const unsigned p = TT | (1u << bit);
                const int c = __popcll(__ballot(k0 == K && t0 >= p)) +
                              __popcll(__ballot(k1 == K && t1 >= p));
                if (c >= r) TT = p;
            }
            s0 = __ballot(k0 == K && t0 >= TT);
            s1 = __ballot(k1 == K && t1 >= TT);
        }

        unsigned* idxq = (unsigned*)pl;                // alias own (consumed) pool
        if ((g0 >> lane) & 1) idxq[mbcnt64(g0)] = t0;
        if ((g1 >> lane) & 1) idxq[__popcll(g0) + mbcnt64(g1)] = t1;
        if ((s0 >> lane) & 1) idxq[m + mbcnt64(s0)] = t0;
        if ((s1 >> lane) & 1) idxq[m + __popcll(s0) + mbcnt64(s1)] = t1;
        myidx[q] = idxq[(lane < KNN) ? lane : 0];
    }

    __syncthreads();   // all pools consumed -> safe to alias as outT

    // ---- epilogue: lane = output channel; neighbors via scalar loads ----
    const int o = lane;
    const float iv   = gamma[o] / sqrtf(var[o] + 1e-5f);
    const float bias = beta[o] - mean[o] * iv;
    const float* Wr = Wm + o * 6;
    const float w0p = Wr[0] * iv, w1p = Wr[1] * iv, w2p = Wr[2] * iv;
    const float w3p = Wr[3] * iv, w4p = Wr[4] * iv, w5p = Wr[5] * iv;

    float* outT = (float*)pool;                        // 64 x (QBLK+1) floats
    #pragma unroll
    for (int q = 0; q < QPW; ++q) {
        const float4 pv = xqb[na + q];                 // scalar reload
        const float basep = fmaf(w3p, pv.x, fmaf(w4p, pv.y, fmaf(w5p, pv.z, bias)));
        const float base2 = basep - fmaf(w0p, pv.x, fmaf(w1p, pv.y, w2p * pv.z));
        float best = -INFINITY;
        #pragma unroll
        for (int k = 0; k < KNN; ++k) {
            const int lk = __builtin_amdgcn_readlane((int)myidx[q], k);
            const int gi = __builtin_amdgcn_readfirstlane((NPTS - 1) - lk);
            const float4 f = xqb[gi];                  // s_load_dwordx4
            float y = fmaf(w0p, f.x, fmaf(w1p, f.y, fmaf(w2p, f.z, base2)));
            y = fmaxf(y, 0.2f * y);                    // LeakyReLU
            best = fmaxf(best, y);
        }
        outT[o * (QBLK + 1) + QPW * w + q] = best;
    }
    __syncthreads();

    // ---- coalesced output: 8 x float4 per channel row, all 512 threads ----
    {
        const int oo = t >> 3, seg = t & 7;
        const int sb = oo * (QBLK + 1) + seg * 4;
        float4 vv;
        vv.x = outT[sb + 0]; vv.y = outT[sb + 1];
        vv.z = outT[sb + 2]; vv.w = outT[sb + 3];
        *(float4*)(out + ((size_t)b * NOUT + oo) * NPTS + n0 + seg * 4) = vv;
    }
}

extern "C" void kernel_launch(void* const* d_in, const int* in_sizes, int n_in,
                              void* d_out, int out_size, void* d_ws, size_t ws_size,
                              hipStream_t stream) {
    const float* x     = (const float*)d_in[0];
    const float* Wm    = (const float*)d_in[1];
    const float* gamma = (const float*)d_in[2];
    const float* beta  = (const float*)d_in[3];
    const float* mean  = (const float*)d_in[4];
    const float* var   = (const float*)d_in[5];
    float* out = (float*)d_out;
    float4* xq = (float4*)d_ws;                    // B*NPTS float4 = 512 KB

    const int B = in_sizes[0] / (3 * NPTS);        // 8
    pack_kernel<<<B * NPTS / 256, 256, 0, stream>>>(x, xq);
    const int nblocks = B * (NPTS / QBLK);         // 8 * 128 = 1024
    edgeconv_kernel<<<nblocks, BLKT, 0, stream>>>(xq, Wm, gamma, beta, mean, var, out);
}

// Round 14
// 136.187 us; speedup vs baseline: 1.0030x; 1.0030x over previous
//
#include <hip/hip_runtime.h>
#include <math.h>

#define NPTS 4096
#define KNN  20
#define NOUT 64
#define WPB  4               // waves per block
#define QPW  4               // queries per wave
#define QBLK (WPB * QPW)     // 16 queries per block
#define BLKT (WPB * 64)      // 256 threads
#define PCAP 128             // per-query pool capacity == selection capacity

// monotone float->uint map (total order preserved)
__device__ __forceinline__ unsigned ord32(float f) {
    unsigned u = __float_as_uint(f);
    int m = ((int)u) >> 31;
    return u ^ ((unsigned)m | 0x80000000u);
}
// inverse of ord32
__device__ __forceinline__ float iord32(unsigned r) {
    unsigned u = (r & 0x80000000u) ? (r ^ 0x80000000u) : ~r;
    return __uint_as_float(u);
}
__device__ __forceinline__ int mbcnt64(unsigned long long m) {
    return __builtin_amdgcn_mbcnt_hi((unsigned)(m >> 32),
           __builtin_amdgcn_mbcnt_lo((unsigned)m, 0));
}

// prologue: xq[b][j] = (x0, x1, x2, -(x0^2+x1^2+x2^2))
__global__ __launch_bounds__(256) void pack_kernel(const float* __restrict__ x,
                                                   float4* __restrict__ xq) {
    const int i = blockIdx.x * 256 + threadIdx.x;   // over B*NPTS
    const int b = i >> 12, j = i & (NPTS - 1);
    const float* xb = x + (size_t)b * 3 * NPTS;
    const float a0 = xb[j], a1 = xb[NPTS + j], a2 = xb[2 * NPTS + j];
    xq[i] = make_float4(a0, a1, a2, -fmaf(a0, a0, fmaf(a1, a1, a2 * a2)));
}

__global__ __launch_bounds__(BLKT, 6) void edgeconv_kernel(
    const float4* __restrict__ xq,    // (B, N) packed points
    const float* __restrict__ Wm,     // (64, 6)
    const float* __restrict__ gamma,
    const float* __restrict__ beta,
    const float* __restrict__ mean,
    const float* __restrict__ var,
    float* __restrict__ out)          // (B, 64, N)
{
    const int bid = blockIdx.x;
    const int b   = bid >> 8;                    // 256 blocks per batch
    const int n0  = (bid & 255) * QBLK;
    const int t    = threadIdx.x;
    const int lane = t & 63;
    const int w    = t >> 6;

    __shared__ unsigned long long pool[QBLK * PCAP];    // 16 KB; outT aliases it
    __shared__ int cnt[QBLK];

    const float4* xqb = xq + (size_t)b * NPTS;

    if (lane < QPW) cnt[QPW * w + lane] = 0;            // own wave's counters

    // ---- query constants (uniform -> scalar loads) ----
    const int na = __builtin_amdgcn_readfirstlane(n0 + QPW * w);
    float q0[QPW], q1[QPW], q2[QPW];
    #pragma unroll
    for (int q = 0; q < QPW; ++q) {
        const float4 pv = xqb[na + q];
        q0[q] = 2.f * pv.x; q1[q] = 2.f * pv.y; q2[q] = 2.f * pv.z;
    }

    // ---- max pass: ALL 4096 candidates, 2 lane-maxima groups per query ----
    float vm0[QPW], vm1[QPW];
    #pragma unroll
    for (int q = 0; q < QPW; ++q) { vm0[q] = -INFINITY; vm1[q] = -INFINITY; }
    #pragma unroll
    for (int g = 0; g < NPTS / 256; ++g) {              // 16 iters of 4 loads
        float4 cc[4];
        #pragma unroll
        for (int u = 0; u < 4; ++u) cc[u] = xqb[(g * 4 + u) * 64 + lane];
        #pragma unroll
        for (int u = 0; u < 4; ++u) {
            #pragma unroll
            for (int q = 0; q < QPW; ++q) {
                const float e = fmaf(q0[q], cc[u].x, fmaf(q1[q], cc[u].y, fmaf(q2[q], cc[u].z, cc[u].w)));
                if (g < 8) vm0[q] = fmaxf(vm0[q], e);
                else       vm1[q] = fmaxf(vm1[q], e);
            }
        }
    }

    // ---- T[q] ~ 20th-largest of 128 group maxima (16-bit ballot bsearch) ----
    // 20 distinct candidates >= T => true 20th-best >= T => superset safe.
    // 16-bit truncation only lowers T (still safe, slightly larger pool).
    float Tf[QPW];
    #pragma unroll
    for (int q = 0; q < QPW; ++q) {
        const unsigned h0 = ord32(vm0[q]) >> 16;
        const unsigned h1 = ord32(vm1[q]) >> 16;
        unsigned K = 0;
        #pragma unroll
        for (int bit = 15; bit >= 0; --bit) {
            const unsigned p = K | (1u << bit);
            const int c = __popcll(__ballot(h0 >= p)) + __popcll(__ballot(h1 >= p));
            if (c >= KNN) K = p;
        }
        Tf[q] = iord32(K << 16);
    }

    const int invl = (NPTS - 1) - lane;

    // ---- filter pass: all 4096 candidates, fused filter+append ----
    #pragma unroll
    for (int g = 0; g < NPTS / 256; ++g) {              // 16 iters of 4 loads
        float4 cc[4];
        #pragma unroll
        for (int u = 0; u < 4; ++u) cc[u] = xqb[(g * 4 + u) * 64 + lane];
        #pragma unroll
        for (int u = 0; u < 4; ++u) {
            const unsigned tag = (unsigned)(invl - (g * 4 + u) * 64);
            #pragma unroll
            for (int q = 0; q < QPW; ++q) {
                const float e = fmaf(q0[q], cc[u].x, fmaf(q1[q], cc[u].y, fmaf(q2[q], cc[u].z, cc[u].w)));
                if (e >= Tf[q]) {
                    const int pos = atomicAdd(&cnt[QPW * w + q], 1);
                    if (pos < PCAP)
                        pool[(QPW * w + q) * PCAP + pos] =
                            ((unsigned long long)ord32(e) << 32) | tag;
                }
            }
        }
    }

    // ---- exact top-20 set per query: 32-bit ballot bsearch, 2 entries/lane ----
    // Order-invariant given the survivor set; cnt <= PCAP handled exactly.
    unsigned myidx[QPW];
    #pragma unroll
    for (int q = 0; q < QPW; ++q) {
        const int pr = QPW * w + q;
        unsigned long long* pl = pool + (size_t)pr * PCAP;
        int cw = __builtin_amdgcn_readfirstlane(cnt[pr]);
        if (cw > PCAP) cw = PCAP;                      // >= 20 guaranteed

        // sentinel 0: ord32(finite) >= 1, so pad entries never counted
        const unsigned long long e0 = (lane < cw) ? pl[lane] : 0ull;
        const unsigned long long e1 = (lane + 64 < cw) ? pl[lane + 64] : 0ull;
        const unsigned k0 = (unsigned)(e0 >> 32), t0 = (unsigned)e0;
        const unsigned k1 = (unsigned)(e1 >> 32), t1 = (unsigned)e1;

        unsigned K = 0;
        #pragma unroll
        for (int bit = 31; bit >= 0; --bit) {
            const unsigned p = K | (1u << bit);
            const int c = __popcll(__ballot(k0 >= p)) + __popcll(__ballot(k1 >= p));
            if (c >= KNN) K = p;
        }

        unsigned long long g0 = __ballot(k0 > K);
        unsigned long long g1 = __ballot(k1 > K);
        const int m = __popcll(g0) + __popcll(g1);     // <= 19
        unsigned long long s0 = __ballot(k0 == K);
        unsigned long long s1 = __ballot(k1 == K);
        const int r = KNN - m;                         // >= 1 ties needed
        if (__popcll(s0) + __popcll(s1) > r) {
            // tie split: choose r ties with largest tag (= lowest index)
            unsigned TT = 0;
            #pragma unroll
            for (int bit = 11; bit >= 0; --bit) {      // tags < 4096
                const unsigned p = TT | (1u << bit);
                const int c = __popcll(__ballot(k0 == K && t0 >= p)) +
                              __popcll(__ballot(k1 == K && t1 >= p));
                if (c >= r) TT = p;
            }
            s0 = __ballot(k0 == K && t0 >= TT);
            s1 = __ballot(k1 == K && t1 >= TT);
        }

        unsigned* idxq = (unsigned*)pl;                // alias own (consumed) pool
        if ((g0 >> lane) & 1) idxq[mbcnt64(g0)] = t0;
        if ((g1 >> lane) & 1) idxq[__popcll(g0) + mbcnt64(g1)] = t1;
        if ((s0 >> lane) & 1) idxq[m + mbcnt64(s0)] = t0;
        if ((s1 >> lane) & 1) idxq[m + __popcll(s0) + mbcnt64(s1)] = t1;
        myidx[q] = idxq[(lane < KNN) ? lane : 0];
    }

    __syncthreads();   // all pools consumed -> safe to alias as outT

    // ---- epilogue: lane = output channel; neighbors via scalar loads ----
    const int o = lane;
    const float iv   = gamma[o] / sqrtf(var[o] + 1e-5f);
    const float bias = beta[o] - mean[o] * iv;
    const float* Wr = Wm + o * 6;
    const float w0p = Wr[0] * iv, w1p = Wr[1] * iv, w2p = Wr[2] * iv;
    const float w3p = Wr[3] * iv, w4p = Wr[4] * iv, w5p = Wr[5] * iv;

    float* outT = (float*)pool;                        // 64 x (QBLK+1) floats
    #pragma unroll
    for (int q = 0; q < QPW; ++q) {
        const float4 pv = xqb[na + q];                 // scalar reload
        const float basep = fmaf(w3p, pv.x, fmaf(w4p, pv.y, fmaf(w5p, pv.z, bias)));
        const float base2 = basep - fmaf(w0p, pv.x, fmaf(w1p, pv.y, w2p * pv.z));
        float best = -INFINITY;
        #pragma unroll
        for (int k = 0; k < KNN; ++k) {
            const int lk = __builtin_amdgcn_readlane((int)myidx[q], k);
            const int gi = __builtin_amdgcn_readfirstlane((NPTS - 1) - lk);
            const float4 f = xqb[gi];                  // s_load_dwordx4
            float y = fmaf(w0p, f.x, fmaf(w1p, f.y, fmaf(w2p, f.z, base2)));
            y = fmaxf(y, 0.2f * y);                    // LeakyReLU
            best = fmaxf(best, y);
        }
        outT[o * (QBLK + 1) + QPW * w + q] = best;
    }
    __syncthreads();

    // ---- coalesced output: one float4 per thread (64 rows x 4 segs) ----
    {
        const int oo = t >> 2, seg = t & 3;
        const int sb = oo * (QBLK + 1) + seg * 4;
        float4 vv;
        vv.x = outT[sb + 0]; vv.y = outT[sb + 1];
        vv.z = outT[sb + 2]; vv.w = outT[sb + 3];
        *(float4*)(out + ((size_t)b * NOUT + oo) * NPTS + n0 + seg * 4) = vv;
    }
}

extern "C" void kernel_launch(void* const* d_in, const int* in_sizes, int n_in,
                              void* d_out, int out_size, void* d_ws, size_t ws_size,
                              hipStream_t stream) {
    const float* x     = (const float*)d_in[0];
    const float* Wm    = (const float*)d_in[1];
    const float* gamma = (const float*)d_in[2];
    const float* beta  = (const float*)d_in[3];
    const float* mean  = (const float*)d_in[4];
    const float* var   = (const float*)d_in[5];
    float* out = (float*)d_out;
    float4* xq = (float4*)d_ws;                    // B*NPTS float4 = 512 KB

    const int B = in_sizes[0] / (3 * NPTS);        // 8
    pack_kernel<<<B * NPTS / 256, 256, 0, stream>>>(x, xq);
    const int nblocks = B * (NPTS / QBLK);         // 8 * 256 = 2048
    edgeconv_kernel<<<nblocks, BLKT, 0, stream>>>(xq, Wm, gamma, beta, mean, var, out);
}

// Round 15
// 129.780 us; speedup vs baseline: 1.0525x; 1.0494x over previous
//
#include <hip/hip_runtime.h>
#include <math.h>

#define NPTS 4096
#define KNN  20
#define NOUT 64
#define WPB  2               // waves per block (barrier-free; packaging only)
#define QPW  4               // queries per wave
#define QBLK (WPB * QPW)     // 8 queries per block
#define BLKT (WPB * 64)      // 128 threads
#define PCAP 128             // per-query pool capacity == selection capacity

// monotone float->uint map (total order preserved)
__device__ __forceinline__ unsigned ord32(float f) {
    unsigned u = __float_as_uint(f);
    int m = ((int)u) >> 31;
    return u ^ ((unsigned)m | 0x80000000u);
}
// inverse of ord32
__device__ __forceinline__ float iord32(unsigned r) {
    unsigned u = (r & 0x80000000u) ? (r ^ 0x80000000u) : ~r;
    return __uint_as_float(u);
}
__device__ __forceinline__ int mbcnt64(unsigned long long m) {
    return __builtin_amdgcn_mbcnt_hi((unsigned)(m >> 32),
           __builtin_amdgcn_mbcnt_lo((unsigned)m, 0));
}

// prologue: xq[b][j] = (x0, x1, x2, -(x0^2+x1^2+x2^2))
__global__ __launch_bounds__(256) void pack_kernel(const float* __restrict__ x,
                                                   float4* __restrict__ xq) {
    const int i = blockIdx.x * 256 + threadIdx.x;   // over B*NPTS
    const int b = i >> 12, j = i & (NPTS - 1);
    const float* xb = x + (size_t)b * 3 * NPTS;
    const float a0 = xb[j], a1 = xb[NPTS + j], a2 = xb[2 * NPTS + j];
    xq[i] = make_float4(a0, a1, a2, -fmaf(a0, a0, fmaf(a1, a1, a2 * a2)));
}

__global__ __launch_bounds__(BLKT, 8) void edgeconv_kernel(
    const float4* __restrict__ xq,    // (B, N) packed points
    const float* __restrict__ Wm,     // (64, 6)
    const float* __restrict__ gamma,
    const float* __restrict__ beta,
    const float* __restrict__ mean,
    const float* __restrict__ var,
    float* __restrict__ out)          // (B, 64, N)
{
    const int bid = blockIdx.x;
    const int b   = bid >> 9;                    // 512 blocks per batch
    const int n0  = (bid & 511) * QBLK;
    const int t    = threadIdx.x;
    const int lane = t & 63;
    const int w    = t >> 6;

    __shared__ unsigned long long pool[QBLK * PCAP];    // 8 KB, wave-private rows
    __shared__ int cnt[QBLK];

    const float4* xqb = xq + (size_t)b * NPTS;

    // own wave's counters only; same-wave DS ops are in-order -> no barrier
    if (lane < QPW) cnt[QPW * w + lane] = 0;

    // ---- query constants (uniform -> scalar loads) ----
    const int na = __builtin_amdgcn_readfirstlane(n0 + QPW * w);
    float q0[QPW], q1[QPW], q2[QPW];
    #pragma unroll
    for (int q = 0; q < QPW; ++q) {
        const float4 pv = xqb[na + q];
        q0[q] = 2.f * pv.x; q1[q] = 2.f * pv.y; q2[q] = 2.f * pv.z;
    }

    // ---- max pass: ALL 4096 candidates, 2 lane-maxima groups per query ----
    float vm0[QPW], vm1[QPW];
    #pragma unroll
    for (int q = 0; q < QPW; ++q) { vm0[q] = -INFINITY; vm1[q] = -INFINITY; }
    #pragma unroll
    for (int g = 0; g < NPTS / 256; ++g) {              // 16 iters of 4 loads
        float4 cc[4];
        #pragma unroll
        for (int u = 0; u < 4; ++u) cc[u] = xqb[(g * 4 + u) * 64 + lane];
        #pragma unroll
        for (int u = 0; u < 4; ++u) {
            #pragma unroll
            for (int q = 0; q < QPW; ++q) {
                const float e = fmaf(q0[q], cc[u].x, fmaf(q1[q], cc[u].y, fmaf(q2[q], cc[u].z, cc[u].w)));
                if (g < 8) vm0[q] = fmaxf(vm0[q], e);
                else       vm1[q] = fmaxf(vm1[q], e);
            }
        }
    }

    // ---- T[q] ~ 20th-largest of 128 group maxima (16-bit ballot bsearch) ----
    // 20 distinct candidates >= T => true 20th-best >= T => superset safe.
    // 16-bit truncation only lowers T (still safe, slightly larger pool).
    float Tf[QPW];
    #pragma unroll
    for (int q = 0; q < QPW; ++q) {
        const unsigned h0 = ord32(vm0[q]) >> 16;
        const unsigned h1 = ord32(vm1[q]) >> 16;
        unsigned K = 0;
        #pragma unroll
        for (int bit = 15; bit >= 0; --bit) {
            const unsigned p = K | (1u << bit);
            const int c = __popcll(__ballot(h0 >= p)) + __popcll(__ballot(h1 >= p));
            if (c >= KNN) K = p;
        }
        Tf[q] = iord32(K << 16);
    }

    const int invl = (NPTS - 1) - lane;

    // ---- filter pass: all 4096 candidates, fused filter+append ----
    #pragma unroll
    for (int g = 0; g < NPTS / 256; ++g) {              // 16 iters of 4 loads
        float4 cc[4];
        #pragma unroll
        for (int u = 0; u < 4; ++u) cc[u] = xqb[(g * 4 + u) * 64 + lane];
        #pragma unroll
        for (int u = 0; u < 4; ++u) {
            const unsigned tag = (unsigned)(invl - (g * 4 + u) * 64);
            #pragma unroll
            for (int q = 0; q < QPW; ++q) {
                const float e = fmaf(q0[q], cc[u].x, fmaf(q1[q], cc[u].y, fmaf(q2[q], cc[u].z, cc[u].w)));
                if (e >= Tf[q]) {
                    const int pos = atomicAdd(&cnt[QPW * w + q], 1);
                    if (pos < PCAP)
                        pool[(QPW * w + q) * PCAP + pos] =
                            ((unsigned long long)ord32(e) << 32) | tag;
                }
            }
        }
    }

    // ---- exact top-20 set per query: 32-bit ballot bsearch, 2 entries/lane ----
    // Wave-private pool; same-wave DS is in-order -> no barrier needed.
    unsigned myidx[QPW];
    #pragma unroll
    for (int q = 0; q < QPW; ++q) {
        const int pr = QPW * w + q;
        unsigned long long* pl = pool + (size_t)pr * PCAP;
        int cw = __builtin_amdgcn_readfirstlane(cnt[pr]);
        if (cw > PCAP) cw = PCAP;                      // >= 20 guaranteed

        // sentinel 0: ord32(finite) >= 1, so pad entries never counted
        const unsigned long long e0 = (lane < cw) ? pl[lane] : 0ull;
        const unsigned long long e1 = (lane + 64 < cw) ? pl[lane + 64] : 0ull;
        const unsigned k0 = (unsigned)(e0 >> 32), t0 = (unsigned)e0;
        const unsigned k1 = (unsigned)(e1 >> 32), t1 = (unsigned)e1;

        unsigned K = 0;
        #pragma unroll
        for (int bit = 31; bit >= 0; --bit) {
            const unsigned p = K | (1u << bit);
            const int c = __popcll(__ballot(k0 >= p)) + __popcll(__ballot(k1 >= p));
            if (c >= KNN) K = p;
        }

        unsigned long long g0 = __ballot(k0 > K);
        unsigned long long g1 = __ballot(k1 > K);
        const int m = __popcll(g0) + __popcll(g1);     // <= 19
        unsigned long long s0 = __ballot(k0 == K);
        unsigned long long s1 = __ballot(k1 == K);
        const int r = KNN - m;                         // >= 1 ties needed
        if (__popcll(s0) + __popcll(s1) > r) {
            // tie split: choose r ties with largest tag (= lowest index)
            unsigned TT = 0;
            #pragma unroll
            for (int bit = 11; bit >= 0; --bit) {      // tags < 4096
                const unsigned p = TT | (1u << bit);
                const int c = __popcll(__ballot(k0 == K && t0 >= p)) +
                              __popcll(__ballot(k1 == K && t1 >= p));
                if (c >= r) TT = p;
            }
            s0 = __ballot(k0 == K && t0 >= TT);
            s1 = __ballot(k1 == K && t1 >= TT);
        }

        unsigned* idxq = (unsigned*)pl;                // alias own (consumed) pool
        if ((g0 >> lane) & 1) idxq[mbcnt64(g0)] = t0;
        if ((g1 >> lane) & 1) idxq[__popcll(g0) + mbcnt64(g1)] = t1;
        if ((s0 >> lane) & 1) idxq[m + mbcnt64(s0)] = t0;
        if ((s1 >> lane) & 1) idxq[m + __popcll(s0) + mbcnt64(s1)] = t1;
        myidx[q] = idxq[(lane < KNN) ? lane : 0];
    }

    // ---- epilogue: lane = output channel; neighbors via scalar loads ----
    const int o = lane;
    const float iv   = gamma[o] / sqrtf(var[o] + 1e-5f);
    const float bias = beta[o] - mean[o] * iv;
    const float* Wr = Wm + o * 6;
    const float w0p = Wr[0] * iv, w1p = Wr[1] * iv, w2p = Wr[2] * iv;
    const float w3p = Wr[3] * iv, w4p = Wr[4] * iv, w5p = Wr[5] * iv;

    float bests[QPW];
    #pragma unroll
    for (int q = 0; q < QPW; ++q) {
        const float4 pv = xqb[na + q];                 // scalar reload
        const float basep = fmaf(w3p, pv.x, fmaf(w4p, pv.y, fmaf(w5p, pv.z, bias)));
        const float base2 = basep - fmaf(w0p, pv.x, fmaf(w1p, pv.y, w2p * pv.z));
        float best = -INFINITY;
        #pragma unroll
        for (int k = 0; k < KNN; ++k) {
            const int lk = __builtin_amdgcn_readlane((int)myidx[q], k);
            const int gi = __builtin_amdgcn_readfirstlane((NPTS - 1) - lk);
            const float4 f = xqb[gi];                  // s_load_dwordx4
            float y = fmaf(w0p, f.x, fmaf(w1p, f.y, fmaf(w2p, f.z, base2)));
            y = fmaxf(y, 0.2f * y);                    // LeakyReLU
            best = fmaxf(best, y);
        }
        bests[q] = best;
    }

    // ---- direct store: lane o writes its 4 consecutive n's as one float4 ----
    float4 res;
    res.x = bests[0]; res.y = bests[1]; res.z = bests[2]; res.w = bests[3];
    *(float4*)(out + ((size_t)b * NOUT + o) * NPTS + na) = res;
}

extern "C" void kernel_launch(void* const* d_in, const int* in_sizes, int n_in,
                              void* d_out, int out_size, void* d_ws, size_t ws_size,
                              hipStream_t stream) {
    const float* x     = (const float*)d_in[0];
    const float* Wm    = (const float*)d_in[1];
    const float* gamma = (const float*)d_in[2];
    const float* beta  = (const float*)d_in[3];
    const float* mean  = (const float*)d_in[4];
    const float* var   = (const float*)d_in[5];
    float* out = (float*)d_out;
    float4* xq = (float4*)d_ws;                    // B*NPTS float4 = 512 KB

    const int B = in_sizes[0] / (3 * NPTS);        // 8
    pack_kernel<<<B * NPTS / 256, 256, 0, stream>>>(x, xq);
    const int nblocks = B * (NPTS / QBLK);         // 8 * 512 = 4096
    edgeconv_kernel<<<nblocks, BLKT, 0, stream>>>(xq, Wm, gamma, beta, mean, var, out);
}